// Round 4
// baseline (76.075 us; speedup 1.0000x reference)
//
#include <hip/hip_runtime.h>
#include <math.h>

#define DIM 512
#define NNBR 8
#define NCTX 16
#define BATCH 1024
#define NB 256            // grid size; all co-resident (8 waves/blk, 1 blk/CU needed)

typedef __attribute__((ext_vector_type(8))) short bf16x8;
typedef __attribute__((ext_vector_type(4))) float f32x4;

// RNE float -> bf16 bits
static __device__ __forceinline__ ushort f2bf(float f) {
    uint u = __float_as_uint(f);
    return (ushort)((u + 0x7fffu + ((u >> 16) & 1u)) >> 16);
}

// grid-wide barrier: ctr pre-zeroed by hipMemsetAsync each launch, used once.
static __device__ __forceinline__ void grid_bar(int* ctr) {
    __syncthreads();
    if (threadIdx.x == 0) {
        __threadfence();                       // release
        atomicAdd(ctr, 1);
        while (atomicAdd(ctr, 0) < NB) { __builtin_amdgcn_s_sleep(1); }
        __threadfence();                       // acquire
    }
    __syncthreads();
}

__global__ __launch_bounds__(512, 2) void k_fused(
    const int* __restrict__ u, const int* __restrict__ v,
    const int* __restrict__ adj_ent, const int* __restrict__ adj_rel,
    const float* __restrict__ usr_emb, const float* __restrict__ ent_emb,
    const float* __restrict__ rel_emb, const float* __restrict__ W_agg,
    const float* __restrict__ b_agg, const float* __restrict__ W_lin,
    const float* __restrict__ b_lin,
    ushort* __restrict__ hidden, ushort* __restrict__ Wb,
    float* __restrict__ out_acc, float* __restrict__ c_acc,
    int* __restrict__ bar,
    float* __restrict__ out, float* __restrict__ c)
{
    const int t = threadIdx.x;
    const int blk = blockIdx.x;

    // ---------------- phase 1: hidden rows (4/block, concurrent) + Wb (2 rows/block) ----------------
    {
        __shared__ int s_ne[4][NNBR], s_nr[4][NNBR];
        __shared__ float s_sc[4][NNBR];
        const int rl = t >> 7;            // row-local 0..3
        const int q = t & 127;            // 128 threads (2 waves) per row
        const int d0 = q * 4;
        const int brow = blk * 4 + rl;
        const int vid = v[brow];
        const int uid = u[brow];
        if (q < NNBR) {
            s_ne[rl][q] = adj_ent[vid * NNBR + q];
            s_nr[rl][q] = adj_rel[vid * NNBR + q];
            s_sc[rl][q] = 0.0f;
        }
        // W_agg -> bf16, 2 rows per block (512 thr x 2 elems)
        {
            const int wrow = blk * 2 + (t >> 8);
            const int wcol = (t & 255) * 2;
            const float2 wv = *(const float2*)&W_agg[(size_t)wrow * DIM + wcol];
            ushort2 o;
            o.x = f2bf(wv.x);
            o.y = f2bf(wv.y);
            *(ushort2*)&Wb[(size_t)wrow * DIM + wcol] = o;
        }
        __syncthreads();

        const float4 user4 = *(const float4*)&usr_emb[(size_t)uid * DIM + d0];
        const float4 self4 = *(const float4*)&ent_emb[(size_t)vid * DIM + d0];
        float4 nbr4[NNBR];
        float p[NNBR];
#pragma unroll
        for (int k = 0; k < NNBR; ++k) {
            nbr4[k] = *(const float4*)&ent_emb[(size_t)s_ne[rl][k] * DIM + d0];
            const float4 r4 = *(const float4*)&rel_emb[(size_t)s_nr[rl][k] * DIM + d0];
            p[k] = user4.x * r4.x + user4.y * r4.y + user4.z * r4.z + user4.w * r4.w;
        }
#pragma unroll
        for (int k = 0; k < NNBR; ++k) {
#pragma unroll
            for (int off = 32; off >= 1; off >>= 1)
                p[k] += __shfl_xor(p[k], off, 64);
        }
        if ((t & 63) == 0) {
#pragma unroll
            for (int k = 0; k < NNBR; ++k) atomicAdd(&s_sc[rl][k], p[k]);
        }
        __syncthreads();

        float m = s_sc[rl][0];
#pragma unroll
        for (int k = 1; k < NNBR; ++k) m = fmaxf(m, s_sc[rl][k]);
        float e[NNBR], ssum = 0.0f;
#pragma unroll
        for (int k = 0; k < NNBR; ++k) { e[k] = expf(s_sc[rl][k] - m); ssum += e[k]; }
        const float inv = 1.0f / ssum;
        float4 agg = {0.0f, 0.0f, 0.0f, 0.0f};
#pragma unroll
        for (int k = 0; k < NNBR; ++k) {
            agg.x = fmaf(e[k], nbr4[k].x, agg.x);
            agg.y = fmaf(e[k], nbr4[k].y, agg.y);
            agg.z = fmaf(e[k], nbr4[k].z, agg.z);
            agg.w = fmaf(e[k], nbr4[k].w, agg.w);
        }
        ushort4 h;
        h.x = f2bf(self4.x + agg.x * inv);
        h.y = f2bf(self4.y + agg.y * inv);
        h.z = f2bf(self4.z + agg.z * inv);
        h.w = f2bf(self4.w + agg.w * inv);
        *(ushort4*)&hidden[(size_t)brow * DIM + d0] = h;
    }

    grid_bar(&bar[0]);

    // ---------------- phase 2: bf16 MFMA GEMM 64x128 tile + fused epilogue (64 blocks) ----------------
    if (blk < 64) {
        __shared__ float c_blk[2][NCTX][128];
        const int bx = blk >> 2, by = blk & 3;
        const int lane = t & 63, w = t >> 6;     // 8 waves: 2(M) x 4(N)
        const int wr = w >> 2, wc = w & 3;
        const int m0 = bx * 64 + wr * 32;
        const int n0 = by * 128 + wc * 32;
        const int r = lane & 15;
        const int kb = lane >> 4;

        f32x4 acc[2][2] = {};
        const ushort* Ap = hidden + (size_t)(m0 + r) * DIM + kb * 8;
        const ushort* Bp = Wb + (size_t)(n0 + r) * DIM + kb * 8;

#pragma unroll
        for (int k0 = 0; k0 < DIM; k0 += 32) {
            bf16x8 a0 = *(const bf16x8*)(Ap + k0);
            bf16x8 a1 = *(const bf16x8*)(Ap + 16 * DIM + k0);
            bf16x8 b0 = *(const bf16x8*)(Bp + k0);
            bf16x8 b1 = *(const bf16x8*)(Bp + 16 * DIM + k0);
            acc[0][0] = __builtin_amdgcn_mfma_f32_16x16x32_bf16(a0, b0, acc[0][0], 0, 0, 0);
            acc[0][1] = __builtin_amdgcn_mfma_f32_16x16x32_bf16(a0, b1, acc[0][1], 0, 0, 0);
            acc[1][0] = __builtin_amdgcn_mfma_f32_16x16x32_bf16(a1, b0, acc[1][0], 0, 0, 0);
            acc[1][1] = __builtin_amdgcn_mfma_f32_16x16x32_bf16(a1, b1, acc[1][1], 0, 0, 0);
        }

        // C/D: col = lane&15 (+16*ni), row = mi*16 + kb*4 + reg
        float cacc[NCTX][2] = {};
#pragma unroll
        for (int mi = 0; mi < 2; ++mi)
#pragma unroll
            for (int j = 0; j < 4; ++j) {
                const int row = m0 + mi * 16 + kb * 4 + j;
                const int uid = u[row];
                float vals[2];
                float dp = 0.0f;
#pragma unroll
                for (int ni = 0; ni < 2; ++ni) {
                    const int col = n0 + ni * 16 + r;
                    const float vv = tanhf(acc[mi][ni][j] + b_agg[col]);
                    vals[ni] = vv;
                    dp = fmaf(vv, usr_emb[(size_t)uid * DIM + col], dp);
                }
#pragma unroll
                for (int n = 0; n < NCTX; ++n) {
                    const float wl = W_lin[n * BATCH + row];
                    cacc[n][0] = fmaf(wl, vals[0], cacc[n][0]);
                    cacc[n][1] = fmaf(wl, vals[1], cacc[n][1]);
                }
                dp += __shfl_xor(dp, 1, 64);
                dp += __shfl_xor(dp, 2, 64);
                dp += __shfl_xor(dp, 4, 64);
                dp += __shfl_xor(dp, 8, 64);
                if (r == 0) atomicAdd(&out_acc[row], dp);
            }

#pragma unroll
        for (int n = 0; n < NCTX; ++n)
#pragma unroll
            for (int ni = 0; ni < 2; ++ni) {
                float vv = cacc[n][ni];
                vv += __shfl_xor(vv, 16, 64);
                vv += __shfl_xor(vv, 32, 64);
                if (kb == 0) c_blk[wr][n][wc * 32 + ni * 16 + r] = vv;
            }
        __syncthreads();

        // 512 threads x 4 elems = 16 n x 128 cols; one atomic per (n,col) per block
#pragma unroll
        for (int e2 = 0; e2 < 4; ++e2) {
            const int idx = t * 4 + e2;
            const int n = idx >> 7, col = idx & 127;
            atomicAdd(&c_acc[(size_t)n * DIM + by * 128 + col],
                      c_blk[0][n][col] + c_blk[1][n][col]);
        }
    }

    grid_bar(&bar[1]);

    // ---------------- phase 3: finishers ----------------
    if (blk < 2) {
        const int i = blk * 512 + t;
        const float x = atomicAdd(&out_acc[i], 0.0f);   // coherent read
        out[i] = 1.0f / (1.0f + expf(-x));
    } else if (blk < 18) {
        const int idx = (blk - 2) * 512 + t;
        const float x = atomicAdd(&c_acc[idx], 0.0f);   // coherent read
        c[idx] = x + b_lin[idx >> 9];
    }
}

extern "C" void kernel_launch(void* const* d_in, const int* in_sizes, int n_in,
                              void* d_out, int out_size, void* d_ws, size_t ws_size,
                              hipStream_t stream) {
    const int*   u       = (const int*)  d_in[0];
    const int*   v       = (const int*)  d_in[1];
    const int*   adj_ent = (const int*)  d_in[2];
    const int*   adj_rel = (const int*)  d_in[3];
    const float* usr_emb = (const float*)d_in[4];
    const float* ent_emb = (const float*)d_in[5];
    const float* rel_emb = (const float*)d_in[6];
    const float* W_agg   = (const float*)d_in[7];
    const float* b_agg   = (const float*)d_in[8];
    const float* W_lin   = (const float*)d_in[9];
    const float* b_lin   = (const float*)d_in[10];

    float* out = (float*)d_out;            // [1024]
    float* c   = out + BATCH;              // [16][512]

    // ws layout: hidden (1MB) | Wb (0.5MB) | out_acc (4KB) | c_acc (32KB) | bar (8B)
    ushort* hidden  = (ushort*)d_ws;
    ushort* Wb      = hidden + (size_t)BATCH * DIM;
    float*  out_acc = (float*)(Wb + (size_t)DIM * DIM);
    float*  c_acc   = out_acc + BATCH;
    int*    bar     = (int*)(c_acc + (size_t)NCTX * DIM);

    // zero accumulators + barrier counters (ws is poisoned, not re-zeroed, by harness)
    hipMemsetAsync(out_acc, 0, (BATCH + NCTX * DIM) * sizeof(float) + 2 * sizeof(int), stream);

    k_fused<<<NB, 512, 0, stream>>>(u, v, adj_ent, adj_rel,
                                    usr_emb, ent_emb, rel_emb, W_agg,
                                    b_agg, W_lin, b_lin,
                                    hidden, Wb, out_acc, c_acc, bar, out, c);
}

// Round 5
// 47.877 us; speedup vs baseline: 1.5890x; 1.5890x over previous
//
#include <hip/hip_runtime.h>
#include <math.h>

#define DIM 512
#define NNBR 8
#define NCTX 16
#define BATCH 1024

typedef __attribute__((ext_vector_type(8))) short bf16x8;
typedef __attribute__((ext_vector_type(4))) float f32x4;

// RNE float -> bf16 bits
static __device__ __forceinline__ ushort f2bf(float f) {
    uint u = __float_as_uint(f);
    return (ushort)((u + 0x7fffu + ((u >> 16) & 1u)) >> 16);
}

// ---------------- K1: hidden (4 rows/block, float4 gathers) + Wb + zero accs ----------------
// 256 blocks x 512 threads; 128 threads (2 waves) per batch row.
__global__ __launch_bounds__(512) void k_hidden(
    const int* __restrict__ u, const int* __restrict__ v,
    const int* __restrict__ adj_ent, const int* __restrict__ adj_rel,
    const float* __restrict__ usr_emb, const float* __restrict__ ent_emb,
    const float* __restrict__ rel_emb, const float* __restrict__ W_agg,
    ushort* __restrict__ hidden, ushort* __restrict__ Wb,
    float* __restrict__ out_acc, float* __restrict__ c_acc,
    int* __restrict__ done)
{
    const int t = threadIdx.x;
    const int blk = blockIdx.x;

    // zero accumulators + ticket (K1 precedes K2 in-stream, so visibility is guaranteed)
    if (blk == 0) {
        out_acc[t] = 0.0f;
        out_acc[512 + t] = 0.0f;
        if (t == 0) *done = 0;
    }
    if (blk >= 1 && blk <= 16) c_acc[(size_t)(blk - 1) * 512 + t] = 0.0f;

    __shared__ int s_ne[4][NNBR], s_nr[4][NNBR];
    __shared__ float s_sc[4][NNBR];
    const int rl = t >> 7;            // row-local 0..3
    const int q = t & 127;            // 128 threads per row
    const int d0 = q * 4;
    const int brow = blk * 4 + rl;
    const int vid = v[brow];
    const int uid = u[brow];
    if (q < NNBR) {
        s_ne[rl][q] = adj_ent[vid * NNBR + q];
        s_nr[rl][q] = adj_rel[vid * NNBR + q];
        s_sc[rl][q] = 0.0f;
    }
    // W_agg -> bf16, 2 rows per block
    {
        const int wrow = blk * 2 + (t >> 8);
        const int wcol = (t & 255) * 2;
        const float2 wv = *(const float2*)&W_agg[(size_t)wrow * DIM + wcol];
        ushort2 o;
        o.x = f2bf(wv.x);
        o.y = f2bf(wv.y);
        *(ushort2*)&Wb[(size_t)wrow * DIM + wcol] = o;
    }
    __syncthreads();

    const float4 user4 = *(const float4*)&usr_emb[(size_t)uid * DIM + d0];
    const float4 self4 = *(const float4*)&ent_emb[(size_t)vid * DIM + d0];
    float4 nbr4[NNBR];
    float p[NNBR];
#pragma unroll
    for (int k = 0; k < NNBR; ++k) {
        nbr4[k] = *(const float4*)&ent_emb[(size_t)s_ne[rl][k] * DIM + d0];
        const float4 r4 = *(const float4*)&rel_emb[(size_t)s_nr[rl][k] * DIM + d0];
        p[k] = user4.x * r4.x + user4.y * r4.y + user4.z * r4.z + user4.w * r4.w;
    }
#pragma unroll
    for (int k = 0; k < NNBR; ++k) {
#pragma unroll
        for (int off = 32; off >= 1; off >>= 1)
            p[k] += __shfl_xor(p[k], off, 64);
    }
    if ((t & 63) == 0) {
#pragma unroll
        for (int k = 0; k < NNBR; ++k) atomicAdd(&s_sc[rl][k], p[k]);
    }
    __syncthreads();

    float m = s_sc[rl][0];
#pragma unroll
    for (int k = 1; k < NNBR; ++k) m = fmaxf(m, s_sc[rl][k]);
    float e[NNBR], ssum = 0.0f;
#pragma unroll
    for (int k = 0; k < NNBR; ++k) { e[k] = expf(s_sc[rl][k] - m); ssum += e[k]; }
    const float inv = 1.0f / ssum;
    float4 agg = {0.0f, 0.0f, 0.0f, 0.0f};
#pragma unroll
    for (int k = 0; k < NNBR; ++k) {
        agg.x = fmaf(e[k], nbr4[k].x, agg.x);
        agg.y = fmaf(e[k], nbr4[k].y, agg.y);
        agg.z = fmaf(e[k], nbr4[k].z, agg.z);
        agg.w = fmaf(e[k], nbr4[k].w, agg.w);
    }
    ushort4 h;
    h.x = f2bf(self4.x + agg.x * inv);
    h.y = f2bf(self4.y + agg.y * inv);
    h.z = f2bf(self4.z + agg.z * inv);
    h.w = f2bf(self4.w + agg.w * inv);
    *(ushort4*)&hidden[(size_t)brow * DIM + d0] = h;
}

// ---------------- K2: fused bf16-MFMA GEMM + tanh + out-dot + c-partials + last-block finish ----------------
// grid (16,8) x 256 thr = 4 waves (2x2 of 32x32), block tile 64x64.
__global__ __launch_bounds__(256) void k_item_fused(
    const ushort* __restrict__ hidden, const ushort* __restrict__ Wb,
    const float* __restrict__ b_agg, const int* __restrict__ u,
    const float* __restrict__ usr_emb, const float* __restrict__ W_lin,
    const float* __restrict__ b_lin,
    float* __restrict__ out_acc, float* __restrict__ c_acc,
    int* __restrict__ done,
    float* __restrict__ out, float* __restrict__ c)
{
    __shared__ float c_blk[2][NCTX][64];
    const int tid = threadIdx.x;
    const int lane = tid & 63, w = tid >> 6;
    const int wr = w >> 1, wc = w & 1;
    const int m0 = blockIdx.x * 64 + wr * 32;
    const int n0 = blockIdx.y * 64 + wc * 32;
    const int r = lane & 15;             // A-row / B-col within frag
    const int kb = lane >> 4;            // k-block (8 elems each)

    f32x4 acc[2][2] = {};
    const ushort* Ap = hidden + (size_t)(m0 + r) * DIM + kb * 8;
    const ushort* Bp = Wb     + (size_t)(n0 + r) * DIM + kb * 8;

#pragma unroll
    for (int k0 = 0; k0 < DIM; k0 += 32) {
        bf16x8 a0 = *(const bf16x8*)(Ap + k0);
        bf16x8 a1 = *(const bf16x8*)(Ap + 16 * DIM + k0);
        bf16x8 b0 = *(const bf16x8*)(Bp + k0);
        bf16x8 b1 = *(const bf16x8*)(Bp + 16 * DIM + k0);
        acc[0][0] = __builtin_amdgcn_mfma_f32_16x16x32_bf16(a0, b0, acc[0][0], 0, 0, 0);
        acc[0][1] = __builtin_amdgcn_mfma_f32_16x16x32_bf16(a0, b1, acc[0][1], 0, 0, 0);
        acc[1][0] = __builtin_amdgcn_mfma_f32_16x16x32_bf16(a1, b0, acc[1][0], 0, 0, 0);
        acc[1][1] = __builtin_amdgcn_mfma_f32_16x16x32_bf16(a1, b1, acc[1][1], 0, 0, 0);
    }

    // C/D layout: col = lane&15 (+16*ni), row = mi*16 + kb*4 + reg
    float cacc[NCTX][2] = {};
#pragma unroll
    for (int mi = 0; mi < 2; ++mi)
#pragma unroll
        for (int j = 0; j < 4; ++j) {
            const int row = m0 + mi * 16 + kb * 4 + j;
            const int uid = u[row];
            float vals[2];
            float dp = 0.0f;
#pragma unroll
            for (int ni = 0; ni < 2; ++ni) {
                const int col = n0 + ni * 16 + r;
                const float vv = tanhf(acc[mi][ni][j] + b_agg[col]);
                vals[ni] = vv;
                dp = fmaf(vv, usr_emb[(size_t)uid * DIM + col], dp);
            }
#pragma unroll
            for (int n = 0; n < NCTX; ++n) {
                const float wl = W_lin[n * BATCH + row];   // uniform across 16-lane group
                cacc[n][0] = fmaf(wl, vals[0], cacc[n][0]);
                cacc[n][1] = fmaf(wl, vals[1], cacc[n][1]);
            }
            dp += __shfl_xor(dp, 1, 64);
            dp += __shfl_xor(dp, 2, 64);
            dp += __shfl_xor(dp, 4, 64);
            dp += __shfl_xor(dp, 8, 64);
            if (r == 0) atomicAdd(&out_acc[row], dp);
        }

#pragma unroll
    for (int n = 0; n < NCTX; ++n)
#pragma unroll
        for (int ni = 0; ni < 2; ++ni) {
            float vv = cacc[n][ni];
            vv += __shfl_xor(vv, 16, 64);
            vv += __shfl_xor(vv, 32, 64);
            if (kb == 0) c_blk[wr][n][wc * 32 + ni * 16 + r] = vv;
        }
    __syncthreads();

    const int base = tid * 4;
#pragma unroll
    for (int e2 = 0; e2 < 4; ++e2) {
        const int idx = base + e2;           // n*64 + col
        const int n = idx >> 6, col = idx & 63;
        atomicAdd(&c_acc[(size_t)n * DIM + blockIdx.y * 64 + col],
                  c_blk[0][n][col] + c_blk[1][n][col]);
    }

    // ---- last-block ticket: 128th block to finish performs the epilogue ----
    __shared__ int s_last;
    __threadfence();                         // make this block's atomics visible
    if (tid == 0) s_last = atomicAdd(done, 1);
    __syncthreads();
    if (s_last == 127) {
#pragma unroll
        for (int i = tid; i < BATCH; i += 256) {
            const float x = atomicAdd(&out_acc[i], 0.0f);   // coherent read
            out[i] = 1.0f / (1.0f + expf(-x));
        }
#pragma unroll
        for (int i = tid; i < NCTX * DIM; i += 256) {
            const float x = atomicAdd(&c_acc[i], 0.0f);     // coherent read
            c[i] = x + b_lin[i >> 9];
        }
    }
}

extern "C" void kernel_launch(void* const* d_in, const int* in_sizes, int n_in,
                              void* d_out, int out_size, void* d_ws, size_t ws_size,
                              hipStream_t stream) {
    const int*   u       = (const int*)  d_in[0];
    const int*   v       = (const int*)  d_in[1];
    const int*   adj_ent = (const int*)  d_in[2];
    const int*   adj_rel = (const int*)  d_in[3];
    const float* usr_emb = (const float*)d_in[4];
    const float* ent_emb = (const float*)d_in[5];
    const float* rel_emb = (const float*)d_in[6];
    const float* W_agg   = (const float*)d_in[7];
    const float* b_agg   = (const float*)d_in[8];
    const float* W_lin   = (const float*)d_in[9];
    const float* b_lin   = (const float*)d_in[10];

    float* out = (float*)d_out;            // [1024]
    float* c   = out + BATCH;              // [16][512]

    // ws layout: hidden (1MB) | Wb (0.5MB) | out_acc (4KB) | c_acc (32KB) | done (4B)
    ushort* hidden  = (ushort*)d_ws;
    ushort* Wb      = hidden + (size_t)BATCH * DIM;
    float*  out_acc = (float*)(Wb + (size_t)DIM * DIM);
    float*  c_acc   = out_acc + BATCH;
    int*    done    = (int*)(c_acc + (size_t)NCTX * DIM);

    k_hidden<<<256, 512, 0, stream>>>(u, v, adj_ent, adj_rel,
                                      usr_emb, ent_emb, rel_emb, W_agg,
                                      hidden, Wb, out_acc, c_acc, done);
    k_item_fused<<<dim3(BATCH / 64, DIM / 64), 256, 0, stream>>>(
        hidden, Wb, b_agg, u, usr_emb, W_lin, b_lin, out_acc, c_acc, done, out, c);
}

// Round 6
// 33.053 us; speedup vs baseline: 2.3016x; 1.4485x over previous
//
#include <hip/hip_runtime.h>
#include <math.h>

#define DIM 512
#define NNBR 8
#define NCTX 16
#define BATCH 1024

typedef __attribute__((ext_vector_type(8))) short bf16x8;
typedef __attribute__((ext_vector_type(4))) float f32x4;

// RNE float -> bf16 bits
static __device__ __forceinline__ ushort f2bf(float f) {
    uint u = __float_as_uint(f);
    return (ushort)((u + 0x7fffu + ((u >> 16) & 1u)) >> 16);
}

// ---------------- K1: hidden_bf[b,d] (one block/row, proven R3 form) + W_agg->bf16 ----------------
__global__ __launch_bounds__(512) void k_hidden(
    const int* __restrict__ u, const int* __restrict__ v,
    const int* __restrict__ adj_ent, const int* __restrict__ adj_rel,
    const float* __restrict__ usr_emb, const float* __restrict__ ent_emb,
    const float* __restrict__ rel_emb, const float* __restrict__ W_agg,
    ushort* __restrict__ hidden_bf, ushort* __restrict__ Wb)
{
    const int b = blockIdx.x;
    const int t = threadIdx.x;           // d index
    if (b < 512) {                        // W_agg -> bf16 (512*512 elems)
        const size_t wi = (size_t)b * 512 + t;
        Wb[wi] = f2bf(W_agg[wi]);
    }
    __shared__ int s_ne[NNBR], s_nr[NNBR];
    __shared__ float s_sc[NNBR];
    const int vid = v[b];
    const int uid = u[b];
    if (t < NNBR) {
        s_ne[t] = adj_ent[vid * NNBR + t];
        s_nr[t] = adj_rel[vid * NNBR + t];
        s_sc[t] = 0.0f;
    }
    __syncthreads();

    const float user_d = usr_emb[(size_t)uid * DIM + t];
    const float self_d = ent_emb[(size_t)vid * DIM + t];
    float nbr[NNBR], p[NNBR];
#pragma unroll
    for (int k = 0; k < NNBR; ++k) {
        nbr[k] = ent_emb[(size_t)s_ne[k] * DIM + t];
        p[k] = user_d * rel_emb[(size_t)s_nr[k] * DIM + t];
    }
#pragma unroll
    for (int k = 0; k < NNBR; ++k) {
#pragma unroll
        for (int off = 32; off >= 1; off >>= 1)
            p[k] += __shfl_xor(p[k], off, 64);
    }
    if ((t & 63) == 0) {
#pragma unroll
        for (int k = 0; k < NNBR; ++k) atomicAdd(&s_sc[k], p[k]);
    }
    __syncthreads();

    float m = s_sc[0];
#pragma unroll
    for (int k = 1; k < NNBR; ++k) m = fmaxf(m, s_sc[k]);
    float e[NNBR], ssum = 0.0f;
#pragma unroll
    for (int k = 0; k < NNBR; ++k) { e[k] = expf(s_sc[k] - m); ssum += e[k]; }
    const float inv = 1.0f / ssum;
    float agg = 0.0f;
#pragma unroll
    for (int k = 0; k < NNBR; ++k) agg = fmaf(e[k], nbr[k], agg);

    hidden_bf[(size_t)b * DIM + t] = f2bf(self_d + agg * inv);
}

// ---------------- K2: fused bf16-MFMA GEMM + tanh + out/c PARTIALS (no atomics) ----------------
// grid (16,8) x 256 thr = 4 waves (2x2 of 32x32), block tile 64x64.
// c_part[bx][n][col512], out_part[by][row]
__global__ __launch_bounds__(256) void k_item_fused(
    const ushort* __restrict__ hidden, const ushort* __restrict__ Wb,
    const float* __restrict__ b_agg, const int* __restrict__ u,
    const float* __restrict__ usr_emb, const float* __restrict__ W_lin,
    float* __restrict__ out_part, float* __restrict__ c_part)
{
    __shared__ float c_blk[2][NCTX][64];
    __shared__ float s_dp[2][64];        // [wc][local row]
    const int tid = threadIdx.x;
    const int lane = tid & 63, w = tid >> 6;
    const int wr = w >> 1, wc = w & 1;
    const int bx = blockIdx.x, by = blockIdx.y;
    const int m0 = bx * 64 + wr * 32;
    const int n0 = by * 64 + wc * 32;
    const int r = lane & 15;             // A-row / B-col within frag
    const int kb = lane >> 4;            // k-block (8 elems each)

    f32x4 acc[2][2] = {};
    const ushort* Ap = hidden + (size_t)(m0 + r) * DIM + kb * 8;
    const ushort* Bp = Wb     + (size_t)(n0 + r) * DIM + kb * 8;

#pragma unroll
    for (int k0 = 0; k0 < DIM; k0 += 32) {
        bf16x8 a0 = *(const bf16x8*)(Ap + k0);
        bf16x8 a1 = *(const bf16x8*)(Ap + 16 * DIM + k0);
        bf16x8 b0 = *(const bf16x8*)(Bp + k0);
        bf16x8 b1 = *(const bf16x8*)(Bp + 16 * DIM + k0);
        acc[0][0] = __builtin_amdgcn_mfma_f32_16x16x32_bf16(a0, b0, acc[0][0], 0, 0, 0);
        acc[0][1] = __builtin_amdgcn_mfma_f32_16x16x32_bf16(a0, b1, acc[0][1], 0, 0, 0);
        acc[1][0] = __builtin_amdgcn_mfma_f32_16x16x32_bf16(a1, b0, acc[1][0], 0, 0, 0);
        acc[1][1] = __builtin_amdgcn_mfma_f32_16x16x32_bf16(a1, b1, acc[1][1], 0, 0, 0);
    }

    // C/D layout: col = lane&15 (+16*ni), row = mi*16 + kb*4 + reg
    float cacc[NCTX][2] = {};
#pragma unroll
    for (int mi = 0; mi < 2; ++mi)
#pragma unroll
        for (int j = 0; j < 4; ++j) {
            const int row = m0 + mi * 16 + kb * 4 + j;
            const int uid = u[row];
            float vals[2];
            float dp = 0.0f;
#pragma unroll
            for (int ni = 0; ni < 2; ++ni) {
                const int col = n0 + ni * 16 + r;
                const float vv = tanhf(acc[mi][ni][j] + b_agg[col]);
                vals[ni] = vv;
                dp = fmaf(vv, usr_emb[(size_t)uid * DIM + col], dp);
            }
#pragma unroll
            for (int n = 0; n < NCTX; ++n) {
                const float wl = W_lin[n * BATCH + row];   // uniform across 16-lane group
                cacc[n][0] = fmaf(wl, vals[0], cacc[n][0]);
                cacc[n][1] = fmaf(wl, vals[1], cacc[n][1]);
            }
            dp += __shfl_xor(dp, 1, 64);
            dp += __shfl_xor(dp, 2, 64);
            dp += __shfl_xor(dp, 4, 64);
            dp += __shfl_xor(dp, 8, 64);
            if (r == 0) s_dp[wc][wr * 32 + mi * 16 + kb * 4 + j] = dp;
        }

#pragma unroll
    for (int n = 0; n < NCTX; ++n)
#pragma unroll
        for (int ni = 0; ni < 2; ++ni) {
            float vv = cacc[n][ni];
            vv += __shfl_xor(vv, 16, 64);
            vv += __shfl_xor(vv, 32, 64);
            if (kb == 0) c_blk[wr][n][wc * 32 + ni * 16 + r] = vv;
        }
    __syncthreads();

    // out partial: row-dp summed over the 2 wc waves -> out_part[by][bx*64 + lr]
    if (tid < 64)
        out_part[(size_t)by * BATCH + bx * 64 + tid] = s_dp[0][tid] + s_dp[1][tid];

    // c partial: float4 store, no atomics: c_part[bx][n][by*64+col]
    {
        const int idx = tid * 4;             // n*64 + col, all 4 in same n
        const int n = idx >> 6, col = idx & 63;
        float4 o;
        o.x = c_blk[0][n][col + 0] + c_blk[1][n][col + 0];
        o.y = c_blk[0][n][col + 1] + c_blk[1][n][col + 1];
        o.z = c_blk[0][n][col + 2] + c_blk[1][n][col + 2];
        o.w = c_blk[0][n][col + 3] + c_blk[1][n][col + 3];
        *(float4*)&c_part[((size_t)bx * NCTX + n) * DIM + by * 64 + col] = o;
    }
}

// ---------------- K3: finisher — plain-load reductions, no atomics ----------------
__global__ __launch_bounds__(256) void k_finish(
    const float* __restrict__ out_part, const float* __restrict__ c_part,
    const float* __restrict__ b_lin, float* __restrict__ out, float* __restrict__ c)
{
    const int i = blockIdx.x * 256 + threadIdx.x;
    if (blockIdx.x < 4) {
        float x = 0.0f;
#pragma unroll
        for (int by = 0; by < 8; ++by) x += out_part[(size_t)by * BATCH + i];
        out[i] = 1.0f / (1.0f + expf(-x));
    } else {
        const int idx = i - 1024;            // 0..8191
        const int n = idx >> 9, col = idx & 511;
        float x = b_lin[n];
#pragma unroll
        for (int bx = 0; bx < 16; ++bx) x += c_part[((size_t)bx * NCTX + n) * DIM + col];
        c[idx] = x;
    }
}

extern "C" void kernel_launch(void* const* d_in, const int* in_sizes, int n_in,
                              void* d_out, int out_size, void* d_ws, size_t ws_size,
                              hipStream_t stream) {
    const int*   u       = (const int*)  d_in[0];
    const int*   v       = (const int*)  d_in[1];
    const int*   adj_ent = (const int*)  d_in[2];
    const int*   adj_rel = (const int*)  d_in[3];
    const float* usr_emb = (const float*)d_in[4];
    const float* ent_emb = (const float*)d_in[5];
    const float* rel_emb = (const float*)d_in[6];
    const float* W_agg   = (const float*)d_in[7];
    const float* b_agg   = (const float*)d_in[8];
    const float* W_lin   = (const float*)d_in[9];
    const float* b_lin   = (const float*)d_in[10];

    float* out = (float*)d_out;            // [1024]
    float* c   = out + BATCH;              // [16][512]

    // ws layout: hidden (1MB) | Wb (0.5MB) | out_part (32KB) | c_part (512KB)
    ushort* hidden   = (ushort*)d_ws;
    ushort* Wb       = hidden + (size_t)BATCH * DIM;
    float*  out_part = (float*)(Wb + (size_t)DIM * DIM);
    float*  c_part   = out_part + 8 * BATCH;

    k_hidden<<<BATCH, 512, 0, stream>>>(u, v, adj_ent, adj_rel,
                                        usr_emb, ent_emb, rel_emb, W_agg,
                                        hidden, Wb);
    k_item_fused<<<dim3(BATCH / 64, DIM / 64), 256, 0, stream>>>(
        hidden, Wb, b_agg, u, usr_emb, W_lin, out_part, c_part);
    k_finish<<<36, 256, 0, stream>>>(out_part, c_part, b_lin, out, c);
}